// Round 6
// baseline (93.867 us; speedup 1.0000x reference)
//
#include <hip/hip_runtime.h>
#include <hip/hip_bf16.h>

#define D 32
#define FACTOR (-1.0f / 128.0f)   // -1/(2*8^2)
#define LOG2E  1.44269504088896340736f

typedef __attribute__((ext_vector_type(8)))  short bf16x8;
typedef __attribute__((ext_vector_type(16))) float f32x16;
typedef __attribute__((ext_vector_type(4)))  float f32x4;

#if __has_builtin(__builtin_amdgcn_exp2f)
#define EXP2(x) __builtin_amdgcn_exp2f(x)
#else
#define EXP2(x) exp2f(x)
#endif

__device__ __forceinline__ ushort bfr(float x) {
    __hip_bfloat16 h = __float2bfloat16(x);     // RNE
    return *reinterpret_cast<ushort*>(&h);
}
__device__ __forceinline__ float bf2f(ushort u) {
    uint w = ((uint)u) << 16;
    return *reinterpret_cast<float*>(&w);
}
__device__ __forceinline__ uint pk2(float a, float b) {
    return (uint)bfr(a) | ((uint)bfr(b) << 16);
}

// ---------------------------------------------------------------------------
// Prep: bf16 copies of X and Y, transposed yT[d][m], x2/y2 from ROUNDED
// values. 4 lanes per row, 8 elements per lane.
// ---------------------------------------------------------------------------
__global__ __launch_bounds__(256) void msk_prep(const float* __restrict__ X,
                                                const float* __restrict__ Y,
                                                ushort* __restrict__ Xb,
                                                ushort* __restrict__ Yb,
                                                ushort* __restrict__ yT,
                                                float* __restrict__ x2,
                                                float* __restrict__ y2,
                                                int N, int M) {
    const int t = blockIdx.x * 256 + threadIdx.x;
    const int i = t >> 2;
    const int c = t & 3;
    if (i >= N + M) return;
    const bool isX = (i < N);
    const int r = isX ? i : i - N;
    const float* src = (isX ? X : Y) + (size_t)r * D + c * 8;

    float4 va = *reinterpret_cast<const float4*>(src);
    float4 vb = *reinterpret_cast<const float4*>(src + 4);
    float f[8] = {va.x, va.y, va.z, va.w, vb.x, vb.y, vb.z, vb.w};

    ushort u[8];
    float s = 0.f;
#pragma unroll
    for (int k = 0; k < 8; ++k) {
        u[k] = bfr(f[k]);
        float g = bf2f(u[k]);
        s = fmaf(g, g, s);
    }
    s += __shfl_xor(s, 1);
    s += __shfl_xor(s, 2);

    uint w[4];
#pragma unroll
    for (int q = 0; q < 4; ++q) w[q] = (uint)u[2 * q] | ((uint)u[2 * q + 1] << 16);

    ushort* dstrow = (isX ? Xb : Yb) + (size_t)r * D + c * 8;
    *reinterpret_cast<uint4*>(dstrow) = *reinterpret_cast<const uint4*>(w);

    if (c == 0) (isX ? x2 : y2)[r] = s;

    if (!isX) {
#pragma unroll
        for (int k = 0; k < 8; ++k)
            yT[(size_t)(c * 8 + k) * M + r] = u[k];
    }
}

// ---------------------------------------------------------------------------
// Main fused kernel, flash-style + software pipeline.
// Block = 4 waves x 32 n = 128 n sharing the m-stream. Per 64-m step:
// cooperative coalesced loads into double-buffered XOR-swizzled LDS.
// Pipeline: GEMM1(t+1) is issued at the TAIL of iteration t (right after the
// barrier), so its MFMA latency is covered by iteration t+1's VALU phase
// (ds_write staging + exp/pack). One barrier per step. setprio(1) around
// MFMA clusters.
// ---------------------------------------------------------------------------
__global__ __launch_bounds__(256) void msk_main(const ushort* __restrict__ Xb,
                                                const ushort* __restrict__ Yb,
                                                const ushort* __restrict__ yT,
                                                const float* __restrict__ x2,
                                                const float* __restrict__ y2,
                                                float* __restrict__ pnom,
                                                float* __restrict__ pden,
                                                int N, int M, int chunk) {
    __shared__ uint4 lYb[2][64][4];   // [buf][m-row][16B slot], slot c at c^(r&3)
    __shared__ uint4 lYT[2][32][8];   // [buf][d-row][16B slot], slot s at s^(d&7)

    const int tid  = threadIdx.x;
    const int lane = tid & 63;
    const int wid  = tid >> 6;
    const int h    = lane >> 5;
    const int ln   = lane & 31;
    const int n0   = blockIdx.x * 128 + wid * 32;
    const int m0b  = blockIdx.y * chunk;
    const int ns   = chunk >> 6;                 // 64-m steps

    const int rY = tid >> 2, cY = tid & 3;       // Yb tile: m-row, 16B col
    const int dT = tid >> 3, sT = tid & 7;       // yT tile: d-row, 16B col

    // x B-fragments: element (h,j) <-> d = 16*ks + 8h + j
    const ushort* xrow = Xb + (size_t)(n0 + ln) * D + h * 8;
    const bf16x8 xf0 = *reinterpret_cast<const bf16x8*>(xrow);
    const bf16x8 xf1 = *reinterpret_cast<const bf16x8*>(xrow + 16);

    const float F2  = FACTOR * LOG2E;
    const float C2  = -2.0f * F2;
    const float xb2 = x2[n0 + ln] * F2;

    f32x16 nom = {};
    float den = 0.f;
    union Fu { uint u[4]; bf16x8 v; };

    uint4 ldYb, ldYT;
    auto issue_loads = [&](int step) {
        const int m = m0b + step * 64;
        ldYb = *(reinterpret_cast<const uint4*>(Yb + (size_t)(m + rY) * D) + cY);
        ldYT = *(reinterpret_cast<const uint4*>(yT + (size_t)dT * M + m) + sT);
    };
    auto stage = [&](int bb) {
        lYb[bb][rY][cY ^ (rY & 3)] = ldYb;
        lYT[bb][dT][sT ^ (dT & 7)] = ldYT;
    };

    f32x16 sA0, sA1;                             // GEMM1 results for current step
    auto gemm1 = [&](int bb) {
        const bf16x8 a00 = *reinterpret_cast<const bf16x8*>(&lYb[bb][ln][(0 + h) ^ (ln & 3)]);
        const bf16x8 a01 = *reinterpret_cast<const bf16x8*>(&lYb[bb][ln][(2 + h) ^ (ln & 3)]);
        const bf16x8 a10 = *reinterpret_cast<const bf16x8*>(&lYb[bb][32 + ln][(0 + h) ^ (ln & 3)]);
        const bf16x8 a11 = *reinterpret_cast<const bf16x8*>(&lYb[bb][32 + ln][(2 + h) ^ (ln & 3)]);
        const f32x16 z = {};
        __builtin_amdgcn_s_setprio(1);
        sA0 = __builtin_amdgcn_mfma_f32_32x32x16_bf16(a00, xf0, z, 0, 0, 0);
        sA1 = __builtin_amdgcn_mfma_f32_32x32x16_bf16(a10, xf0, z, 0, 0, 0);
        sA0 = __builtin_amdgcn_mfma_f32_32x32x16_bf16(a01, xf1, sA0, 0, 0, 0);
        sA1 = __builtin_amdgcn_mfma_f32_32x32x16_bf16(a11, xf1, sA1, 0, 0, 0);
        __builtin_amdgcn_s_setprio(0);
        // sA reg r: m = m0 + tile*32 + (r&3) + 8*(r>>2) + 4h ; n = n0 + ln
    };

    auto expack = [&](const f32x16& s, int mt, uint* pw) {
#pragma unroll
        for (int r4 = 0; r4 < 4; ++r4) {
            f32x4 yv = *reinterpret_cast<const f32x4*>(y2 + mt + r4 * 8 + h * 4);
            float kq[4];
#pragma unroll
            for (int q = 0; q < 4; ++q)
                kq[q] = EXP2(fmaf(s[r4 * 4 + q], C2, fmaf(yv[q], F2, xb2)));
            den += (kq[0] + kq[1]) + (kq[2] + kq[3]);
            pw[r4 * 2 + 0] = pk2(kq[0], kq[1]);
            pw[r4 * 2 + 1] = pk2(kq[2], kq[3]);
        }
    };

    // Prologue: stage step 0, prefetch step 1, GEMM1(0).
    issue_loads(0);
    stage(0);
    if (ns > 1) issue_loads(1);
    __syncthreads();
    gemm1(0);

    for (int t = 0; t < ns; ++t) {
        const int b  = t & 1;
        const int m0 = m0b + t * 64;

        if (t + 1 < ns) {
            stage((t + 1) & 1);                  // buf_next last read at step t-1
            if (t + 2 < ns) issue_loads(t + 2);  // HBM/L2 latency under this VALU phase
        }

        // exp/pack for both 32-m halves (covers GEMM1's MFMA latency)
        uint pw0[8], pw1[8];
        expack(sA0, m0, pw0);
        expack(sA1, m0 + 32, pw1);

        Fu p00, p01, p10, p11;
#pragma unroll
        for (int q = 0; q < 4; ++q) {
            p00.u[q] = pw0[q]; p01.u[q] = pw0[q + 4];
            p10.u[q] = pw1[q]; p11.u[q] = pw1[q + 4];
        }

        // GEMM2 B-frags from LDS yT tile row ln
        const uint2* yr = reinterpret_cast<const uint2*>(&lYT[b][ln][0]);
        const int sw = ln & 7;
        Fu b00, b01, b10, b11;
        *reinterpret_cast<uint2*>(&b00.u[0]) = yr[(0 ^ sw) * 2 + h];
        *reinterpret_cast<uint2*>(&b00.u[2]) = yr[(1 ^ sw) * 2 + h];
        *reinterpret_cast<uint2*>(&b01.u[0]) = yr[(2 ^ sw) * 2 + h];
        *reinterpret_cast<uint2*>(&b01.u[2]) = yr[(3 ^ sw) * 2 + h];
        *reinterpret_cast<uint2*>(&b10.u[0]) = yr[(4 ^ sw) * 2 + h];
        *reinterpret_cast<uint2*>(&b10.u[2]) = yr[(5 ^ sw) * 2 + h];
        *reinterpret_cast<uint2*>(&b11.u[0]) = yr[(6 ^ sw) * 2 + h];
        *reinterpret_cast<uint2*>(&b11.u[2]) = yr[(7 ^ sw) * 2 + h];

        __builtin_amdgcn_s_setprio(1);
        nom = __builtin_amdgcn_mfma_f32_32x32x16_bf16(p00.v, b00.v, nom, 0, 0, 0);
        nom = __builtin_amdgcn_mfma_f32_32x32x16_bf16(p01.v, b01.v, nom, 0, 0, 0);
        nom = __builtin_amdgcn_mfma_f32_32x32x16_bf16(p10.v, b10.v, nom, 0, 0, 0);
        nom = __builtin_amdgcn_mfma_f32_32x32x16_bf16(p11.v, b11.v, nom, 0, 0, 0);
        __builtin_amdgcn_s_setprio(0);

        if (t + 1 < ns) {
            __syncthreads();                     // stage(t+1) visible; buf[b] reads done
            gemm1((t + 1) & 1);                  // MFMA overlaps next iter's VALU phase
        }
    }

    // den: halves hold disjoint m partials for the same n=ln
    den += __shfl_xor(den, 32);

    const size_t base = (size_t)blockIdx.y * N;
#pragma unroll
    for (int r = 0; r < 16; ++r) {
        const int row = (r & 3) + 8 * (r >> 2) + 4 * h;      // n offset
        pnom[(base + n0 + row) * 32 + ln] = nom[r];          // d = ln
    }
    if (h == 0) pden[base + n0 + ln] = den;
}

// ---------------------------------------------------------------------------
// Reduce over m-chunks and divide.
// ---------------------------------------------------------------------------
__global__ __launch_bounds__(256) void msk_reduce(const float* __restrict__ pnom,
                                                  const float* __restrict__ pden,
                                                  float* __restrict__ out,
                                                  int N, int S) {
    const int t = blockIdx.x * blockDim.x + threadIdx.x;
    if (t >= N * 32) return;
    const int n = t >> 5;
    float nom = 0.f, den = 0.f;
    for (int s = 0; s < S; ++s) {
        nom += pnom[(size_t)s * N * 32 + t];
        den += pden[(size_t)s * N + n];
    }
    out[t] = nom / den;
}

// ---------------------------------------------------------------------------
extern "C" void kernel_launch(void* const* d_in, const int* in_sizes, int n_in,
                              void* d_out, int out_size, void* d_ws, size_t ws_size,
                              hipStream_t stream) {
    const float* X = (const float*)d_in[0];
    const float* Y = (const float*)d_in[1];
    float* out     = (float*)d_out;

    const int N = in_sizes[0] / D;   // 8192
    const int M = in_sizes[1] / D;   // 8192

    char* p = (char*)d_ws;
    ushort* Xb = (ushort*)p; p += (size_t)N * D * sizeof(ushort);
    ushort* Yb = (ushort*)p; p += (size_t)M * D * sizeof(ushort);
    ushort* yT = (ushort*)p; p += (size_t)M * D * sizeof(ushort);
    float*  x2 = (float*)p;  p += (size_t)N * sizeof(float);
    float*  y2 = (float*)p;  p += (size_t)M * sizeof(float);
    size_t used = (size_t)(p - (char*)d_ws);
    used = (used + 255) & ~(size_t)255;

    const size_t per_s = (size_t)N * 33 * sizeof(float);
    int S = 16;                                  // 1024 blocks = 4/CU
    while (S > 1 && used + (size_t)S * per_s > ws_size) S >>= 1;
    const int chunk = M / S;                     // 512 -> 8 steps of 64 m

    float* pnom = (float*)((char*)d_ws + used);
    float* pden = pnom + (size_t)S * N * 32;

    msk_prep<<<dim3(((N + M) * 4 + 255) / 256), dim3(256), 0, stream>>>(
        X, Y, Xb, Yb, yT, x2, y2, N, M);

    msk_main<<<dim3(N / 128, S), dim3(256), 0, stream>>>(
        Xb, Yb, yT, x2, y2, pnom, pden, N, M, chunk);

    msk_reduce<<<dim3((N * 32 + 255) / 256), dim3(256), 0, stream>>>(
        pnom, pden, out, N, S);
}